// Round 7
// baseline (15133.156 us; speedup 1.0000x reference)
//
#include <hip/hip_runtime.h>
#include <math.h>

typedef _Float16 f16;
typedef __attribute__((ext_vector_type(8))) _Float16 half8;
typedef __attribute__((ext_vector_type(4))) float f32x4;

static __device__ __forceinline__ float sigmoid_f(float x) { return 1.0f / (1.0f + expf(-x)); }

// exact split: x == (float)hi + (float)lo / 4096 (lo pre-scaled to dodge denormals)
static __device__ __forceinline__ void splitf(float x, f16& hi, f16& lo) {
    hi = (f16)x;
    float r = x - (float)hi;
    lo = (f16)(r * 4096.0f);
}

// ---------------------------------------------------------------------------
// Tap-decomposed implicit-GEMM conv device function (same math as round 6,
// which validated at absmax 1.66e-2): f16 MFMA, 2-term activation split,
// fp32 accumulate, no LDS/barriers/boundary branches (halo=2 padded cats).
// Wave owns NG*16 px x NOC*16 oc.  MODE 0 zr / 1 h~ / 2 plain conv.
// ---------------------------------------------------------------------------
template <int KH, int KW, int K, int MODE, int NG, int NOC, int D,
          int CS, int KOFF, int HIN, int WIN, int HOUT, int WOUT,
          int OC, int STRIDE, int PAD, int OCS, int OKOFF>
__device__ __forceinline__ void gemm_dev(
    int bx, int by, int bz,
    const f16* Ah, const f16* Al,
    const f16* __restrict__ Wt, const float* __restrict__ bias,
    const float* __restrict__ zbuf, float* __restrict__ zout,
    f16* Oh, f16* Ol)
{
    constexpr int WP   = WIN + 4;
    constexpr int HPW  = (HIN + 4) * WP;
    constexpr int OWP  = WOUT + 4;
    constexpr int OHPW = (HOUT + 4) * OWP;
    constexpr int WSH  = (WOUT == 64) ? 6 : ((WOUT == 32) ? 5 : 4);
    constexpr int KPT  = K / 32;
    constexpr int NSTEP = KH * KW * KPT;
    static_assert(NSTEP % D == 0, "NSTEP divisible by D");

    const int lane = threadIdx.x & 63;
    const int wave = threadIdx.x >> 6;
    const int pixbase = (bx * 4 + wave) * (NG * 16);
    const int klane = (lane >> 4) * 8;
    const int ocl   = lane & 15;
    const int ocb   = by * (NOC * 16);

    const f16* ph[NG];
    const f16* pl[NG];
#pragma unroll
    for (int g = 0; g < NG; ++g) {
        int apix = pixbase + 16 * g + ocl;
        int y = apix >> WSH, x = apix & (WOUT - 1);
        size_t o = ((size_t)bz * HPW + (size_t)(y * STRIDE - PAD + 2) * WP +
                    (x * STRIDE - PAD + 2)) * CS + KOFF + klane;
        ph[g] = Ah + o;
        pl[g] = Al + o;
    }
    const f16* pw = Wt + (size_t)(ocb + ocl) * K + klane;

    int lk = 0, lkx = 0;
    auto advance = [&]() {
#pragma unroll
        for (int g = 0; g < NG; ++g) { ph[g] += 32; pl[g] += 32; }
        pw += 32;
        if (++lk == KPT) {
            lk = 0;
            int pixstep = 1;
            if (++lkx == KW) { lkx = 0; pixstep = WP - (KW - 1); }
            const long ad = (long)pixstep * CS - K;
#pragma unroll
            for (int g = 0; g < NG; ++g) { ph[g] += ad; pl[g] += ad; }
            pw += (long)(OC - 1) * K;
        }
    };

    half8 bh[D][NG], bl[D][NG], bw[D][NOC];
    f32x4 acc[NG][NOC] = {};
    f32x4 acc2[NG][NOC] = {};

#pragma unroll
    for (int s = 0; s < D - 1; ++s) {
#pragma unroll
        for (int g = 0; g < NG; ++g) {
            bh[s][g] = *(const half8*)ph[g];
            bl[s][g] = *(const half8*)pl[g];
        }
#pragma unroll
        for (int j = 0; j < NOC; ++j)
            bw[s][j] = *(const half8*)(pw + (size_t)j * 16 * K);
        advance();
    }

#pragma unroll 1
    for (int ii = 0; ii < NSTEP / D; ++ii) {
#pragma unroll
        for (int d = 0; d < D; ++d) {
            const int ls = (d + D - 1) % D;
#pragma unroll
            for (int g = 0; g < NG; ++g) {
                bh[ls][g] = *(const half8*)ph[g];
                bl[ls][g] = *(const half8*)pl[g];
            }
#pragma unroll
            for (int j = 0; j < NOC; ++j)
                bw[ls][j] = *(const half8*)(pw + (size_t)j * 16 * K);
            advance();
#pragma unroll
            for (int j = 0; j < NOC; ++j)
#pragma unroll
                for (int g = 0; g < NG; ++g) {
                    acc[g][j]  = __builtin_amdgcn_mfma_f32_16x16x32_f16(bh[d][g], bw[d][j], acc[g][j], 0, 0, 0);
                    acc2[g][j] = __builtin_amdgcn_mfma_f32_16x16x32_f16(bl[d][g], bw[d][j], acc2[g][j], 0, 0, 0);
                }
        }
    }

    constexpr int Cc = (MODE == 0) ? (OC >> 1) : OC;
#pragma unroll
    for (int g = 0; g < NG; ++g) {
#pragma unroll
        for (int j = 0; j < NOC; ++j) {
            const int oc = ocb + j * 16 + ocl;
            const float bv = bias[oc];
#pragma unroll
            for (int r = 0; r < 4; ++r) {
                const int pix = pixbase + 16 * g + ((lane >> 4) << 2) + r;
                const int y = pix >> WSH, x = pix & (WOUT - 1);
                const size_t pp = (size_t)bz * OHPW + (size_t)(y + 2) * OWP + (x + 2);
                const size_t pz = (size_t)bz * (HOUT * WOUT) + pix;
                float a = acc[g][j][r] + acc2[g][j][r] * (1.0f / 4096.0f) + bv;
                if (MODE == 0) {
                    float s = sigmoid_f(a);
                    if (oc < Cc) {
                        zout[pz * Cc + oc] = s;
                    } else {
                        size_t hidx = pp * OCS + (oc - Cc);
                        float hv = (float)Ah[hidx] + (float)Al[hidx] * (1.0f / 4096.0f);
                        float rh = s * hv;
                        f16 hi, lo; splitf(rh, hi, lo);
                        size_t oi = pp * OCS + Cc + oc;  // channel 2C + (oc-C)
                        Oh[oi] = hi; Ol[oi] = lo;
                    }
                } else if (MODE == 1) {
                    size_t hidx = pp * OCS + oc;
                    float hv = (float)Ah[hidx] + (float)Al[hidx] * (1.0f / 4096.0f);
                    float zv = zbuf[pz * Cc + oc];
                    float hn = (1.f - zv) * hv + zv * tanhf(a);
                    f16 hi, lo; splitf(hn, hi, lo);
                    Oh[hidx] = hi; Ol[hidx] = lo;
                } else {
                    f16 hi, lo; splitf(a, hi, lo);
                    size_t oi = pp * OCS + OKOFF + oc;
                    Oh[oi] = hi; Ol[oi] = lo;
                }
            }
        }
    }
}

// conv1 device: IC=1, k4 s2 p1, 128x128 -> 64x64, OC=64, fp32 direct; writes
// f16 hi/lo into padded cat1 xt region (ch [64,128), CS=192, halo 2).
static __device__ __forceinline__ void conv1_dev(
    int bx, int bz, const float* __restrict__ in, const float* __restrict__ w,
    const float* __restrict__ bias, f16* Oh, f16* Ol)
{
    const int tid = threadIdx.x;
    const int px  = bx * 64 + (tid & 63);
    const int ocg = tid >> 6;
    const int y = px >> 6, x = px & 63;
    const float* src = in + (size_t)bz * 196608;
    float v[16];
#pragma unroll
    for (int ky = 0; ky < 4; ++ky)
#pragma unroll
        for (int kx = 0; kx < 4; ++kx) {
            int iy = 2 * y - 1 + ky, ix = 2 * x - 1 + kx;
            v[ky * 4 + kx] = ((unsigned)iy < 128u && (unsigned)ix < 128u) ? src[iy * 128 + ix] : 0.f;
        }
    size_t obase = ((size_t)bz * 4624 + (size_t)(y + 2) * 68 + (x + 2)) * 192 + 64 + ocg * 16;
#pragma unroll
    for (int o = 0; o < 16; ++o) {
        int oc = ocg * 16 + o;
        float s = bias[oc];
        const float* wr = w + oc * 16;
#pragma unroll
        for (int t = 0; t < 16; ++t) s += wr[t] * v[t];
        f16 hi, lo; splitf(s, hi, lo);
        Oh[obase + o] = hi; Ol[obase + o] = lo;
    }
}

// ---------------------------------------------------------------------------
// Fused superstep phases.  Independent sub-problems dispatched by block range.
// A: conv1[s] (512) | c2[s-1] (512) | c3[s-2] (256)          -> 1280 blocks
// B: zr1[s] (1024)  | zr2[s-1] (1024) | zr3[s-2] (256)       -> 2304 blocks
// C: h1[s] (1024)   | h2[s-1] (512)  | h3[s-2] (128)         -> 1664 blocks
// ---------------------------------------------------------------------------
__global__ __launch_bounds__(256) void phaseA(
    const float* __restrict__ input, const float* __restrict__ c1w, const float* __restrict__ c1b,
    const f16* __restrict__ wt_c2, const float* __restrict__ c2b,
    const f16* __restrict__ wt_c3, const float* __restrict__ c3b,
    f16* cat1h, f16* cat1l, f16* cat2h, f16* cat2l, f16* cat3h, f16* cat3l,
    int t1, int a2, int a3)
{
    const int bid = blockIdx.x;
    if (bid < 512) {
        if (t1 < 0) return;
        conv1_dev(bid & 63, bid >> 6, input + (size_t)t1 * 16384, c1w, c1b, cat1h, cat1l);
    } else if (bid < 1024) {
        if (!a2) return;
        int r = bid - 512;
        gemm_dev<4, 4, 64, 2, 1, 2, 4, 192, 0, 64, 64, 32, 32, 128, 2, 1, 384, 128>(
            r & 15, (r >> 4) & 3, r >> 6,
            cat1h, cat1l, wt_c2, c2b, nullptr, nullptr, cat2h, cat2l);
    } else {
        if (!a3) return;
        int r = bid - 1024;
        gemm_dev<4, 4, 128, 2, 1, 1, 4, 384, 0, 32, 32, 16, 16, 128, 2, 1, 384, 128>(
            r & 3, (r >> 2) & 7, r >> 5,
            cat2h, cat2l, wt_c3, c3b, nullptr, nullptr, cat3h, cat3l);
    }
}

__global__ __launch_bounds__(256) void phaseB(
    f16* cat1h, f16* cat1l, f16* cat2h, f16* cat2l, f16* cat3h, f16* cat3l,
    const f16* __restrict__ w1, const float* __restrict__ b1,
    const f16* __restrict__ w2, const float* __restrict__ b2,
    const f16* __restrict__ w3, const float* __restrict__ b3,
    float* z1, float* z2, float* z3,
    int a1, int a2, int a3)
{
    const int bid = blockIdx.x;
    if (bid < 1024) {
        if (!a1) return;
        int r = bid;
        gemm_dev<5, 5, 128, 0, 1, 4, 2, 192, 0, 64, 64, 64, 64, 128, 1, 2, 192, 0>(
            r & 63, (r >> 6) & 1, r >> 7,
            cat1h, cat1l, w1, b1, nullptr, z1, cat1h, cat1l);
    } else if (bid < 2048) {
        if (!a2) return;
        int r = bid - 1024;
        gemm_dev<5, 5, 256, 0, 1, 2, 4, 384, 0, 32, 32, 32, 32, 256, 1, 2, 384, 0>(
            r & 15, (r >> 4) & 7, r >> 7,
            cat2h, cat2l, w2, b2, nullptr, z2, cat2h, cat2l);
    } else {
        if (!a3) return;
        int r = bid - 2048;
        gemm_dev<5, 5, 256, 0, 1, 2, 4, 384, 0, 16, 16, 16, 16, 256, 1, 2, 384, 0>(
            r & 3, (r >> 2) & 7, r >> 5,
            cat3h, cat3l, w3, b3, nullptr, z3, cat3h, cat3l);
    }
}

__global__ __launch_bounds__(256) void phaseC(
    f16* cat1h, f16* cat1l, f16* cat2h, f16* cat2l, f16* cat3h, f16* cat3l,
    const f16* __restrict__ w1, const float* __restrict__ b1,
    const f16* __restrict__ w2, const float* __restrict__ b2,
    const f16* __restrict__ w3, const float* __restrict__ b3,
    const float* __restrict__ z1, const float* __restrict__ z2, const float* __restrict__ z3,
    int a1, int a2, int a3)
{
    const int bid = blockIdx.x;
    if (bid < 1024) {
        if (!a1) return;
        int r = bid;
        gemm_dev<5, 5, 128, 1, 1, 2, 4, 192, 64, 64, 64, 64, 64, 64, 1, 2, 192, 0>(
            r & 63, (r >> 6) & 1, r >> 7,
            cat1h, cat1l, w1, b1, z1, nullptr, cat1h, cat1l);
    } else if (bid < 1536) {
        if (!a2) return;
        int r = bid - 1024;
        gemm_dev<5, 5, 256, 1, 1, 2, 4, 384, 128, 32, 32, 32, 32, 128, 1, 2, 384, 0>(
            r & 15, (r >> 4) & 3, r >> 6,
            cat2h, cat2l, w2, b2, z2, nullptr, cat2h, cat2l);
    } else {
        if (!a3) return;
        int r = bid - 1536;
        gemm_dev<5, 5, 256, 1, 1, 2, 4, 384, 128, 16, 16, 16, 16, 128, 1, 2, 384, 0>(
            r & 3, (r >> 2) & 3, r >> 4,
            cat3h, cat3l, w3, b3, z3, nullptr, cat3h, cat3l);
    }
}

// w[oc][ic][kh][kw] fp32 -> wt [tap][oc][ic'] f16 (RNE).
// perm=1: swap input-channel halves (zr convs: ref concat [x,h] -> cat [h,xt]).
__global__ __launch_bounds__(256) void prep_w(
    const float* __restrict__ w, f16* __restrict__ wt,
    int OC, int IC, int KK, int perm)
{
    int i = blockIdx.x * 256 + threadIdx.x;
    int total = OC * IC * KK;
    if (i >= total) return;
    int oc = i / (IC * KK);
    int r  = i - oc * (IC * KK);
    int ic = r / KK;
    int tap = r - ic * KK;
    int icn = perm ? ((ic < IC / 2) ? ic + IC / 2 : ic - IC / 2) : ic;
    wt[((size_t)tap * OC + oc) * IC + icn] = (f16)w[i];
}

// padded cat hi/lo h-region -> fp32 NCHW
__global__ __launch_bounds__(256) void cat_to_nchw(
    const f16* __restrict__ hi, const f16* __restrict__ lo,
    float* __restrict__ dst, int C, int HW, int wsh, int WP, int HPW, int CS)
{
    int i = blockIdx.x * 256 + threadIdx.x;
    int b = i / (C * HW);
    int r = i - b * (C * HW);
    int c = r / HW;
    int p = r - c * HW;
    int y = p >> wsh, x = p & ((1 << wsh) - 1);
    size_t s = ((size_t)b * HPW + (size_t)(y + 2) * WP + (x + 2)) * CS + c;
    dst[i] = (float)hi[s] + (float)lo[s] * (1.0f / 4096.0f);
}

// ---------------------------------------------------------------------------
extern "C" void kernel_launch(void* const* d_in, const int* in_sizes, int n_in,
                              void* d_out, int out_size, void* d_ws, size_t ws_size,
                              hipStream_t stream)
{
    (void)in_sizes; (void)n_in; (void)out_size; (void)ws_size;

    const float* input  = (const float*)d_in[0];
    const float* c1_w   = (const float*)d_in[1];
    const float* c1_b   = (const float*)d_in[2];
    const float* g1zr_w = (const float*)d_in[3];
    const float* g1zr_b = (const float*)d_in[4];
    const float* g1h_w  = (const float*)d_in[5];
    const float* g1h_b  = (const float*)d_in[6];
    const float* c2_w   = (const float*)d_in[7];
    const float* c2_b   = (const float*)d_in[8];
    const float* g2zr_w = (const float*)d_in[9];
    const float* g2zr_b = (const float*)d_in[10];
    const float* g2h_w  = (const float*)d_in[11];
    const float* g2h_b  = (const float*)d_in[12];
    const float* c3_w   = (const float*)d_in[13];
    const float* c3_b   = (const float*)d_in[14];
    const float* g3zr_w = (const float*)d_in[15];
    const float* g3zr_b = (const float*)d_in[16];
    const float* g3h_w  = (const float*)d_in[17];
    const float* g3h_b  = (const float*)d_in[18];

    float* out1 = (float*)d_out;                 // [8,64,64,64]  NCHW
    float* out2 = (float*)d_out + 2097152;       // [8,128,32,32]
    float* out3 = (float*)d_out + 3145728;       // [8,128,16,16]

    char* ws = (char*)d_ws;
    size_t off = 0;
    auto takeB = [&](size_t bytes) { char* p = ws + off; off += (bytes + 255) & ~(size_t)255; return p; };

    // weights (+slack for pipeline overrun reads)
    const size_t WSLACK = 300000;
    f16* wt_g1zr = (f16*)takeB((size_t)25 * 128 * 128 * 2 + WSLACK);
    f16* wt_g1h  = (f16*)takeB((size_t)25 * 64 * 128 * 2 + WSLACK);
    f16* wt_c2   = (f16*)takeB((size_t)16 * 128 * 64 * 2 + WSLACK);
    f16* wt_g2zr = (f16*)takeB((size_t)25 * 256 * 256 * 2 + WSLACK);
    f16* wt_g2h  = (f16*)takeB((size_t)25 * 128 * 256 * 2 + WSLACK);
    f16* wt_c3   = (f16*)takeB((size_t)16 * 128 * 128 * 2 + WSLACK);
    f16* wt_g3zr = (f16*)takeB((size_t)25 * 256 * 256 * 2 + WSLACK);
    f16* wt_g3h  = (f16*)takeB((size_t)25 * 128 * 256 * 2 + WSLACK);

    // padded cat buffers (halo=2): [h | xt | rh] per pixel, f16 hi/lo planes
    const size_t cat1_n = (size_t)8 * 4624 * 192;  // 68x68, CS=192
    const size_t cat2_n = (size_t)8 * 1296 * 384;  // 36x36, CS=384
    const size_t cat3_n = (size_t)8 * 400 * 384;   // 20x20, CS=384
    const size_t ASLACK = 65536;
    f16* cat1h = (f16*)takeB(cat1_n * 2 + ASLACK);
    f16* cat1l = (f16*)takeB(cat1_n * 2 + ASLACK);
    f16* cat2h = (f16*)takeB(cat2_n * 2 + ASLACK);
    f16* cat2l = (f16*)takeB(cat2_n * 2 + ASLACK);
    f16* cat3h = (f16*)takeB(cat3_n * 2 + ASLACK);
    f16* cat3l = (f16*)takeB(cat3_n * 2 + ASLACK);
    float* z1 = (float*)takeB((size_t)8 * 4096 * 64 * 4);
    float* z2 = (float*)takeB((size_t)8 * 1024 * 128 * 4);
    float* z3 = (float*)takeB((size_t)8 * 256 * 128 * 4);

    hipMemsetAsync(cat1h, 0, cat1_n * 2, stream);
    hipMemsetAsync(cat1l, 0, cat1_n * 2, stream);
    hipMemsetAsync(cat2h, 0, cat2_n * 2, stream);
    hipMemsetAsync(cat2l, 0, cat2_n * 2, stream);
    hipMemsetAsync(cat3h, 0, cat3_n * 2, stream);
    hipMemsetAsync(cat3l, 0, cat3_n * 2, stream);

    auto prep = [&](const float* w, f16* wt, int OC, int IC, int KK, int perm) {
        int total = OC * IC * KK;
        prep_w<<<(total + 255) / 256, 256, 0, stream>>>(w, wt, OC, IC, KK, perm);
    };
    prep(g1zr_w, wt_g1zr, 128, 128, 25, 1);
    prep(g1h_w,  wt_g1h,  64, 128, 25, 0);
    prep(c2_w,   wt_c2,   128, 64, 16, 0);
    prep(g2zr_w, wt_g2zr, 256, 256, 25, 1);
    prep(g2h_w,  wt_g2h,  128, 256, 25, 0);
    prep(c3_w,   wt_c3,   128, 128, 16, 0);
    prep(g3zr_w, wt_g3zr, 256, 256, 25, 1);
    prep(g3h_w,  wt_g3h,  128, 256, 25, 0);

    // software-pipelined stage schedule: superstep s runs stage1 at t=s,
    // stage2 at t=s-1, stage3 at t=s-2 (all mutually independent per phase).
    for (int s = 0; s < 14; ++s) {
        const int t1 = (s < 12) ? s : -1;
        const int a1 = (s < 12) ? 1 : 0;
        const int a2 = (s >= 1 && s <= 12) ? 1 : 0;
        const int a3 = (s >= 2) ? 1 : 0;
        phaseA<<<1280, 256, 0, stream>>>(
            input, c1_w, c1_b, wt_c2, c2_b, wt_c3, c3_b,
            cat1h, cat1l, cat2h, cat2l, cat3h, cat3l, t1, a2, a3);
        phaseB<<<2304, 256, 0, stream>>>(
            cat1h, cat1l, cat2h, cat2l, cat3h, cat3l,
            wt_g1zr, g1zr_b, wt_g2zr, g2zr_b, wt_g3zr, g3zr_b,
            z1, z2, z3, a1, a2, a3);
        phaseC<<<1664, 256, 0, stream>>>(
            cat1h, cat1l, cat2h, cat2l, cat3h, cat3l,
            wt_g1h, g1h_b, wt_g2h, g2h_b, wt_g3h, g3h_b,
            z1, z2, z3, a1, a2, a3);
    }

    cat_to_nchw<<<8192, 256, 0, stream>>>(cat1h, cat1l, out1, 64, 4096, 6, 68, 4624, 192);
    cat_to_nchw<<<4096, 256, 0, stream>>>(cat2h, cat2l, out2, 128, 1024, 5, 36, 1296, 384);
    cat_to_nchw<<<1024, 256, 0, stream>>>(cat3h, cat3l, out3, 128, 256, 4, 20, 400, 384);
}

// Round 8
// 5390.864 us; speedup vs baseline: 2.8072x; 2.8072x over previous
//
#include <hip/hip_runtime.h>
#include <math.h>

typedef _Float16 f16;
typedef __attribute__((ext_vector_type(8))) _Float16 half8;
typedef __attribute__((ext_vector_type(4))) float f32x4;

static __device__ __forceinline__ float sigmoid_f(float x) { return 1.0f / (1.0f + expf(-x)); }

// exact split: x == (float)hi + (float)lo / 4096 (lo pre-scaled to dodge denormals)
static __device__ __forceinline__ void splitf(float x, f16& hi, f16& lo) {
    hi = (f16)x;
    float r = x - (float)hi;
    lo = (f16)(r * 4096.0f);
}

// ---------------------------------------------------------------------------
// Tap-decomposed implicit-GEMM conv, f16 MFMA, 2-term activation split,
// fp32 accumulate.  COALESCED layouts:
//   A: [b][cblk][pixP][32ch] f16 hi/lo planes (padded halo=2).  One A-frag
//      load (16 px x 32k) = contiguous 1 KB.
//   B: [tap][ocblk][kblk]{[kgrp4][oc16][ch8]} -> load = base + lane*16B,
//      contiguous 1 KB.
// Wave owns NG*16 px x NOC*16 oc; D-deep register ping-pong over flat
// (tap x kblk) steps; per-tap advance is a uniform pointer bump.
// A-frag: lane&15=pixel, k=(lane>>4)*8+j ; B-frag: lane&15=oc, same k.
// D-frag: col(oc)=lane&15, row(pixel)=(lane>>4)*4+reg  [HW-verified layouts]
// MODE 0: zr -> z=sigmoid fp32 (oc<C); rh=sigmoid*h -> cat ch[2C..3C)
// MODE 1: h~ -> h' = (1-z)*h + z*tanh  -> cat ch[0..C)
// MODE 2: conv+bias -> next-stage cat xt region (ch base OCH0)
// ---------------------------------------------------------------------------
template <int KH, int KW, int KPT, int MODE, int NG, int NOC, int D,
          int CBI, int KB0, int WPI, int PIXPI,
          int WSH, int HWOUT, int OC, int STRIDE, int POFF,
          int CBO, int OCH0, int WPO, int PIXPO>
__global__ __launch_bounds__(256) void gemm_conv(
    const f16* Ah, const f16* Al, const f16* __restrict__ Wt,
    const float* __restrict__ bias, const float* __restrict__ zbuf,
    float* zout, f16* Oh, f16* Ol)
{
    constexpr int NSTEP = KH * KW * KPT;
    constexpr int WOUT  = 1 << WSH;
    constexpr int OCB   = OC / 16;
    static_assert(NSTEP % D == 0, "NSTEP divisible by D");

    const int lane = threadIdx.x & 63;
    const int wave = threadIdx.x >> 6;
    const int b    = blockIdx.z;
    const int pixbase = (blockIdx.x * 4 + wave) * (NG * 16);
    const int ocbase  = blockIdx.y * (NOC * 16);

    const f16* ph[NG];
    const f16* pl[NG];
#pragma unroll
    for (int g = 0; g < NG; ++g) {
        int apix = pixbase + 16 * g + (lane & 15);
        int y = apix >> WSH, x = apix & (WOUT - 1);
        int p0 = (y * STRIDE + POFF) * WPI + (x * STRIDE + POFF);
        size_t o = ((size_t)(b * CBI + KB0) * PIXPI + p0) * 32 + (lane >> 4) * 8;
        ph[g] = Ah + o;
        pl[g] = Al + o;
    }
    const f16* pw = Wt + (size_t)(blockIdx.y * NOC) * (KPT * 512) + lane * 8;

    int lk = 0, lkx = 0;
    auto advance = [&]() {
#pragma unroll
        for (int g = 0; g < NG; ++g) { ph[g] += (size_t)PIXPI * 32; pl[g] += (size_t)PIXPI * 32; }
        pw += 512;
        if (++lk == KPT) {
            lk = 0;
            int shift = 1;
            if (++lkx == KW) { lkx = 0; shift = WPI - (KW - 1); }
            const long ad = (long)shift * 32 - (long)KPT * PIXPI * 32;
#pragma unroll
            for (int g = 0; g < NG; ++g) { ph[g] += ad; pl[g] += ad; }
            pw += (size_t)(OCB - 1) * (KPT * 512);
        }
    };

    half8 bh[D][NG], bl[D][NG], bw[D][NOC];
    f32x4 acc[NG][NOC] = {};
    f32x4 acc2[NG][NOC] = {};

#pragma unroll
    for (int s = 0; s < D - 1; ++s) {
#pragma unroll
        for (int g = 0; g < NG; ++g) {
            bh[s][g] = *(const half8*)ph[g];
            bl[s][g] = *(const half8*)pl[g];
        }
#pragma unroll
        for (int j = 0; j < NOC; ++j)
            bw[s][j] = *(const half8*)(pw + (size_t)j * (KPT * 512));
        advance();
    }

#pragma unroll 1
    for (int ii = 0; ii < NSTEP / D; ++ii) {
#pragma unroll
        for (int d = 0; d < D; ++d) {
            const int ls = (d + D - 1) % D;
#pragma unroll
            for (int g = 0; g < NG; ++g) {
                bh[ls][g] = *(const half8*)ph[g];
                bl[ls][g] = *(const half8*)pl[g];
            }
#pragma unroll
            for (int j = 0; j < NOC; ++j)
                bw[ls][j] = *(const half8*)(pw + (size_t)j * (KPT * 512));
            advance();
#pragma unroll
            for (int j = 0; j < NOC; ++j)
#pragma unroll
                for (int g = 0; g < NG; ++g) {
                    acc[g][j]  = __builtin_amdgcn_mfma_f32_16x16x32_f16(bh[d][g], bw[d][j], acc[g][j], 0, 0, 0);
                    acc2[g][j] = __builtin_amdgcn_mfma_f32_16x16x32_f16(bl[d][g], bw[d][j], acc2[g][j], 0, 0, 0);
                }
        }
    }

    constexpr int Cc = (MODE == 0) ? (OC >> 1) : OC;
#pragma unroll
    for (int g = 0; g < NG; ++g) {
#pragma unroll
        for (int j = 0; j < NOC; ++j) {
            const int oc = ocbase + j * 16 + (lane & 15);
            const float bv = bias[oc];
#pragma unroll
            for (int r = 0; r < 4; ++r) {
                const int pix = pixbase + 16 * g + ((lane >> 4) << 2) + r;
                const int y = pix >> WSH, x = pix & (WOUT - 1);
                const int pr = (y + 2) * WPI + (x + 2);
                const int pwr = (y + 2) * WPO + (x + 2);
                const size_t pz = (size_t)b * HWOUT + pix;
                float a = acc[g][j][r] + acc2[g][j][r] * (1.0f / 4096.0f) + bv;
                if (MODE == 0) {
                    float s = sigmoid_f(a);
                    if (oc < Cc) {
                        zout[pz * Cc + oc] = s;
                    } else {
                        int hch = oc - Cc;
                        size_t hidx = ((size_t)(b * CBI + (hch >> 5)) * PIXPI + pr) * 32 + (hch & 31);
                        float hv = (float)Ah[hidx] + (float)Al[hidx] * (1.0f / 4096.0f);
                        float rh = s * hv;
                        f16 hi, lo; splitf(rh, hi, lo);
                        int wch = Cc + oc;  // = 2C + (oc-C)
                        size_t widx = ((size_t)(b * CBO + (wch >> 5)) * PIXPO + pwr) * 32 + (wch & 31);
                        Oh[widx] = hi; Ol[widx] = lo;
                    }
                } else if (MODE == 1) {
                    size_t hidx = ((size_t)(b * CBI + (oc >> 5)) * PIXPI + pr) * 32 + (oc & 31);
                    float hv = (float)Ah[hidx] + (float)Al[hidx] * (1.0f / 4096.0f);
                    float zv = zbuf[pz * Cc + oc];
                    float hn = (1.f - zv) * hv + zv * tanhf(a);
                    f16 hi, lo; splitf(hn, hi, lo);
                    Oh[hidx] = hi; Ol[hidx] = lo;
                } else {
                    f16 hi, lo; splitf(a, hi, lo);
                    int wch = OCH0 + oc;
                    size_t widx = ((size_t)(b * CBO + (wch >> 5)) * PIXPO + pwr) * 32 + (wch & 31);
                    Oh[widx] = hi; Ol[widx] = lo;
                }
            }
        }
    }
}

// ---------------------------------------------------------------------------
// conv1: IC=1, k4 s2 p1, 128x128 -> 64x64, OC=64, fp32 direct; writes f16
// hi/lo into blocked cat1 xt region (ch [64,128), cblk 2..3, halo 2).
// ---------------------------------------------------------------------------
__global__ __launch_bounds__(256) void conv1_k(
    const float* __restrict__ in, const float* __restrict__ w,
    const float* __restrict__ bias, f16* Oh, f16* Ol)
{
    const int b   = blockIdx.y;
    const int tid = threadIdx.x;
    const int px  = blockIdx.x * 64 + (tid & 63);
    const int ocg = tid >> 6;
    const int y = px >> 6, x = px & 63;
    const float* src = in + (size_t)b * 196608;
    float v[16];
#pragma unroll
    for (int ky = 0; ky < 4; ++ky)
#pragma unroll
        for (int kx = 0; kx < 4; ++kx) {
            int iy = 2 * y - 1 + ky, ix = 2 * x - 1 + kx;
            v[ky * 4 + kx] = ((unsigned)iy < 128u && (unsigned)ix < 128u) ? src[iy * 128 + ix] : 0.f;
        }
    const int p = (y + 2) * 68 + (x + 2);
#pragma unroll
    for (int o = 0; o < 16; ++o) {
        int ch = 64 + ocg * 16 + o;
        float s = bias[ch - 64];
        const float* wr = w + (ch - 64) * 16;
#pragma unroll
        for (int t = 0; t < 16; ++t) s += wr[t] * v[t];
        f16 hi, lo; splitf(s, hi, lo);
        size_t idx = ((size_t)(b * 6 + (ch >> 5)) * 4624 + p) * 32 + (ch & 31);
        Oh[idx] = hi; Ol[idx] = lo;
    }
}

// w[oc][ic][kh][kw] fp32 -> blocked f16 [tap][ocblk][kblk][kgrp4][oc16][ch8].
// perm=1: swap input-channel halves (zr convs: ref concat [x,h] -> cat [h,xt]).
__global__ __launch_bounds__(256) void prep_w(
    const float* __restrict__ w, f16* __restrict__ wt,
    int OC, int IC, int KK, int perm)
{
    int i = blockIdx.x * 256 + threadIdx.x;
    int total = OC * IC * KK;
    if (i >= total) return;
    int oc = i / (IC * KK);
    int r  = i - oc * (IC * KK);
    int ic = r / KK;
    int tap = r - ic * KK;
    int icn = perm ? ((ic < IC / 2) ? ic + IC / 2 : ic - IC / 2) : ic;
    int OCB = OC >> 4, KPT = IC >> 5;
    int ob = oc >> 4, ol = oc & 15;
    int kb = icn >> 5, kg = (icn >> 3) & 3, ch = icn & 7;
    size_t o = (((size_t)tap * OCB + ob) * KPT + kb) * 512 + kg * 128 + ol * 8 + ch;
    wt[o] = (f16)w[i];
}

// blocked cat hi/lo h-region -> fp32 NCHW
__global__ __launch_bounds__(256) void cat_to_nchw(
    const f16* __restrict__ hi, const f16* __restrict__ lo,
    float* __restrict__ dst, int C, int HW, int wsh, int WP, int PIXP, int CB)
{
    int i = blockIdx.x * 256 + threadIdx.x;
    int b = i / (C * HW);
    int r = i - b * (C * HW);
    int c = r / HW;
    int p = r - c * HW;
    int y = p >> wsh, x = p & ((1 << wsh) - 1);
    size_t s = ((size_t)(b * CB + (c >> 5)) * PIXP + (size_t)(y + 2) * WP + (x + 2)) * 32 + (c & 31);
    dst[i] = (float)hi[s] + (float)lo[s] * (1.0f / 4096.0f);
}

// ---------------------------------------------------------------------------
extern "C" void kernel_launch(void* const* d_in, const int* in_sizes, int n_in,
                              void* d_out, int out_size, void* d_ws, size_t ws_size,
                              hipStream_t stream)
{
    (void)in_sizes; (void)n_in; (void)out_size; (void)ws_size;

    const float* input  = (const float*)d_in[0];
    const float* c1_w   = (const float*)d_in[1];
    const float* c1_b   = (const float*)d_in[2];
    const float* g1zr_w = (const float*)d_in[3];
    const float* g1zr_b = (const float*)d_in[4];
    const float* g1h_w  = (const float*)d_in[5];
    const float* g1h_b  = (const float*)d_in[6];
    const float* c2_w   = (const float*)d_in[7];
    const float* c2_b   = (const float*)d_in[8];
    const float* g2zr_w = (const float*)d_in[9];
    const float* g2zr_b = (const float*)d_in[10];
    const float* g2h_w  = (const float*)d_in[11];
    const float* g2h_b  = (const float*)d_in[12];
    const float* c3_w   = (const float*)d_in[13];
    const float* c3_b   = (const float*)d_in[14];
    const float* g3zr_w = (const float*)d_in[15];
    const float* g3zr_b = (const float*)d_in[16];
    const float* g3h_w  = (const float*)d_in[17];
    const float* g3h_b  = (const float*)d_in[18];

    float* out1 = (float*)d_out;                 // [8,64,64,64]  NCHW
    float* out2 = (float*)d_out + 2097152;       // [8,128,32,32]
    float* out3 = (float*)d_out + 3145728;       // [8,128,16,16]

    char* ws = (char*)d_ws;
    size_t off = 0;
    auto takeB = [&](size_t bytes) { char* p = ws + off; off += (bytes + 255) & ~(size_t)255; return p; };

    const size_t WSLACK = 400000;
    f16* wt_g1zr = (f16*)takeB((size_t)25 * 128 * 128 * 2 + WSLACK);
    f16* wt_g1h  = (f16*)takeB((size_t)25 * 64 * 128 * 2 + WSLACK);
    f16* wt_c2   = (f16*)takeB((size_t)16 * 128 * 64 * 2 + WSLACK);
    f16* wt_g2zr = (f16*)takeB((size_t)25 * 256 * 256 * 2 + WSLACK);
    f16* wt_g2h  = (f16*)takeB((size_t)25 * 128 * 256 * 2 + WSLACK);
    f16* wt_c3   = (f16*)takeB((size_t)16 * 128 * 128 * 2 + WSLACK);
    f16* wt_g3zr = (f16*)takeB((size_t)25 * 256 * 256 * 2 + WSLACK);
    f16* wt_g3h  = (f16*)takeB((size_t)25 * 128 * 256 * 2 + WSLACK);

    // blocked padded cat buffers: [b][cblk][pixP][32], hi/lo planes
    const size_t cat1_n = (size_t)8 * 6 * 4624 * 32;   // 68x68, 192ch
    const size_t cat2_n = (size_t)8 * 12 * 1296 * 32;  // 36x36, 384ch
    const size_t cat3_n = (size_t)8 * 12 * 400 * 32;   // 20x20, 384ch
    const size_t ASLACK = 1 << 20;
    f16* cat1h = (f16*)takeB(cat1_n * 2 + ASLACK);
    f16* cat1l = (f16*)takeB(cat1_n * 2 + ASLACK);
    f16* cat2h = (f16*)takeB(cat2_n * 2 + ASLACK);
    f16* cat2l = (f16*)takeB(cat2_n * 2 + ASLACK);
    f16* cat3h = (f16*)takeB(cat3_n * 2 + ASLACK);
    f16* cat3l = (f16*)takeB(cat3_n * 2 + ASLACK);
    float* z1 = (float*)takeB((size_t)8 * 4096 * 64 * 4);
    float* z2 = (float*)takeB((size_t)8 * 1024 * 128 * 4);
    float* z3 = (float*)takeB((size_t)8 * 256 * 128 * 4);

    hipMemsetAsync(cat1h, 0, cat1_n * 2, stream);
    hipMemsetAsync(cat1l, 0, cat1_n * 2, stream);
    hipMemsetAsync(cat2h, 0, cat2_n * 2, stream);
    hipMemsetAsync(cat2l, 0, cat2_n * 2, stream);
    hipMemsetAsync(cat3h, 0, cat3_n * 2, stream);
    hipMemsetAsync(cat3l, 0, cat3_n * 2, stream);

    auto prep = [&](const float* w, f16* wt, int OC, int IC, int KK, int perm) {
        int total = OC * IC * KK;
        prep_w<<<(total + 255) / 256, 256, 0, stream>>>(w, wt, OC, IC, KK, perm);
    };
    prep(g1zr_w, wt_g1zr, 128, 128, 25, 1);
    prep(g1h_w,  wt_g1h,  64, 128, 25, 0);
    prep(c2_w,   wt_c2,   128, 64, 16, 0);
    prep(g2zr_w, wt_g2zr, 256, 256, 25, 1);
    prep(g2h_w,  wt_g2h,  128, 256, 25, 0);
    prep(c3_w,   wt_c3,   128, 128, 16, 0);
    prep(g3zr_w, wt_g3zr, 256, 256, 25, 1);
    prep(g3h_w,  wt_g3h,  128, 256, 25, 0);

    for (int t = 0; t < 12; ++t) {
        // stage 1 @64x64, cat1: 6 cblks [h(0-1)|xt(2-3)|rh(4-5)]
        conv1_k<<<dim3(64, 8), 256, 0, stream>>>(
            input + (size_t)t * 16384, c1_w, c1_b, cat1h, cat1l);
        gemm_conv<5, 5, 4, 0, 2, 4, 2, 6, 0, 68, 4624, 6, 4096, 128, 1, 0, 6, 0, 68, 4624>
            <<<dim3(32, 2, 8), 256, 0, stream>>>(
            cat1h, cat1l, wt_g1zr, g1zr_b, nullptr, z1, cat1h, cat1l);
        gemm_conv<5, 5, 4, 1, 1, 4, 4, 6, 2, 68, 4624, 6, 4096, 64, 1, 0, 6, 0, 68, 4624>
            <<<dim3(64, 1, 8), 256, 0, stream>>>(
            cat1h, cat1l, wt_g1h, g1h_b, z1, nullptr, cat1h, cat1l);
        // c2: reads stage-1 h (cblk 0-1), writes stage-2 xt (ch 128..255)
        gemm_conv<4, 4, 2, 2, 1, 4, 4, 6, 0, 68, 4624, 5, 1024, 128, 2, 1, 12, 128, 36, 1296>
            <<<dim3(16, 2, 8), 256, 0, stream>>>(
            cat1h, cat1l, wt_c2, c2_b, nullptr, nullptr, cat2h, cat2l);
        // stage 2 @32x32, cat2: 12 cblks [h(0-3)|xt(4-7)|rh(8-11)]
        gemm_conv<5, 5, 8, 0, 1, 4, 4, 12, 0, 36, 1296, 5, 1024, 256, 1, 0, 12, 0, 36, 1296>
            <<<dim3(16, 4, 8), 256, 0, stream>>>(
            cat2h, cat2l, wt_g2zr, g2zr_b, nullptr, z2, cat2h, cat2l);
        gemm_conv<5, 5, 8, 1, 1, 4, 4, 12, 4, 36, 1296, 5, 1024, 128, 1, 0, 12, 0, 36, 1296>
            <<<dim3(16, 2, 8), 256, 0, stream>>>(
            cat2h, cat2l, wt_g2h, g2h_b, z2, nullptr, cat2h, cat2l);
        // c3: reads stage-2 h (cblk 0-3), writes stage-3 xt (ch 128..255)
        gemm_conv<4, 4, 4, 2, 1, 2, 4, 12, 0, 36, 1296, 4, 256, 128, 2, 1, 12, 128, 20, 400>
            <<<dim3(4, 4, 8), 256, 0, stream>>>(
            cat2h, cat2l, wt_c3, c3_b, nullptr, nullptr, cat3h, cat3l);
        // stage 3 @16x16, cat3: 12 cblks
        gemm_conv<5, 5, 8, 0, 1, 2, 4, 12, 0, 20, 400, 4, 256, 256, 1, 0, 12, 0, 20, 400>
            <<<dim3(4, 8, 8), 256, 0, stream>>>(
            cat3h, cat3l, wt_g3zr, g3zr_b, nullptr, z3, cat3h, cat3l);
        gemm_conv<5, 5, 8, 1, 1, 2, 4, 12, 4, 20, 400, 4, 256, 128, 1, 0, 12, 0, 20, 400>
            <<<dim3(4, 4, 8), 256, 0, stream>>>(
            cat3h, cat3l, wt_g3h, g3h_b, z3, nullptr, cat3h, cat3l);
    }

    cat_to_nchw<<<8192, 256, 0, stream>>>(cat1h, cat1l, out1, 64, 4096, 6, 68, 4624, 6);
    cat_to_nchw<<<4096, 256, 0, stream>>>(cat2h, cat2l, out2, 128, 1024, 5, 36, 1296, 12);
    cat_to_nchw<<<1024, 256, 0, stream>>>(cat3h, cat3l, out3, 128, 256, 4, 20, 400, 12);
}